// Round 1
// baseline (371.996 us; speedup 1.0000x reference)
//
#include <hip/hip_runtime.h>

// Problem constants (reference: B=8, N=512, D=64, H=64)
#define NB 8
#define NN 512
#define ND 64
#define NH 64

// ws layout (float offsets):
//     0 : Wm packed   [NH*ND]   = 4096
//  4096 : WqdT        [ND*NH]   = 4096   (Wq+Wd, transposed)
//  8192 : WkdT        [ND*NH]   = 4096   (Wk-Wd, transposed)
// 12288 : hq_pre      [NB*NN*NH] = 262144  (x@(Wq+Wd)^T + b1)
// 274432: hkT         [NB*NH*NN] = 262144  (x@(Wk-Wd)^T, transposed to [b,h,n])
#define WS_WM   0
#define WS_WQDT 4096
#define WS_WKDT 8192
#define WS_HQ   12288
#define WS_HKT  274432

__global__ __launch_bounds__(256) void k0_weights(const float* __restrict__ W1,
                                                  float* __restrict__ ws) {
    int t = threadIdx.x;
    float* wm   = ws + WS_WM;
    float* wqdT = ws + WS_WQDT;
    float* wkdT = ws + WS_WKDT;
    for (int i = 0; i < 16; ++i) {
        int idx = t + i * 256;       // 0..4095
        int h = idx >> 6, d = idx & 63;
        float wq = W1[h * 256 + d];
        float wk = W1[h * 256 + 64 + d];
        float wd = W1[h * 256 + 128 + d];
        float wmv = W1[h * 256 + 192 + d];
        wm[h * 64 + d] = wmv;
        wqdT[d * 64 + h] = wq + wd;
        wkdT[d * 64 + h] = wk - wd;
    }
}

__global__ __launch_bounds__(256) void k1_proj(const float* __restrict__ x,
                                               const float* __restrict__ b1,
                                               float* __restrict__ ws) {
    const float* wqdT = ws + WS_WQDT;
    const float* wkdT = ws + WS_WKDT;
    float* hq  = ws + WS_HQ;
    float* hkT = ws + WS_HKT;
    __shared__ float xs[256];
    int t = threadIdx.x;
    int r0 = blockIdx.x * 4;                 // 4 rows (b*NN+n) per block
    xs[t] = x[r0 * 64 + t];
    __syncthreads();
    int r = t >> 6, h = t & 63;
    const float* xr = xs + r * 64;
    float aq = b1[h], ak = 0.f;
    #pragma unroll
    for (int d = 0; d < 64; ++d) {
        float xv = xr[d];
        aq += xv * wqdT[d * 64 + h];
        ak += xv * wkdT[d * 64 + h];
    }
    int row = r0 + r;
    hq[row * 64 + h] = aq;
    int b = row >> 9, n = row & (NN - 1);
    hkT[(b * 64 + h) * NN + n] = ak;
}

// One block per (b,q); 256 threads; one thread per key within a 256-key tile.
__global__ __launch_bounds__(256) void k2_main(const float* __restrict__ x,
                                               const float* __restrict__ vm,
                                               const float* __restrict__ prelu_a,
                                               const float* __restrict__ W2,
                                               const float* __restrict__ b2,
                                               const float* __restrict__ ws,
                                               float* __restrict__ out) {
    const float* wm  = ws + WS_WM;     // [NH][64], block-uniform -> s_load path
    const float* hq  = ws + WS_HQ;     // [B*N][64]
    const float* hkT = ws + WS_HKT;    // [B][64][N]

    int t  = threadIdx.x;
    int bq = blockIdx.x;
    int b  = bq >> 9, q = bq & (NN - 1);

    const float* hqv = hq + bq * 64;               // uniform
    const float* hkb = hkT + b * 64 * NN;          // uniform base
    const float* xb  = x + b * NN * 64;

    float pa  = prelu_a[0];
    float b2v = b2[0];

    __shared__ float xq_sh[64];
    __shared__ float s_sh[256];
    if (t < 64) xq_sh[t] = x[bq * 64 + t];
    __syncthreads();

    int dlane   = t & 63;     // epilogue: this thread's d
    int quarter = t >> 6;     // epilogue: this thread's key sub-range
    float enc = 0.f;

    for (int k0 = 0; k0 <= q; k0 += 256) {
        int k = k0 + t;
        float score = 0.f;
        if (k <= q) {
            // c[d] = x_q[d] * x_k[d] in registers
            float c[64];
            const float* xk = xb + k * 64;
            #pragma unroll
            for (int d = 0; d < 64; d += 4) {
                float4 v = *(const float4*)(xk + d);
                c[d]     = v.x * xq_sh[d];
                c[d + 1] = v.y * xq_sh[d + 1];
                c[d + 2] = v.z * xq_sh[d + 2];
                c[d + 3] = v.w * xq_sh[d + 3];
            }
            score = b2v;
            for (int h = 0; h < 64; ++h) {
                const float* wr = wm + h * 64;   // uniform address -> SMEM
                float a0 = 0.f, a1 = 0.f, a2 = 0.f, a3 = 0.f;
                #pragma unroll
                for (int d = 0; d < 64; d += 4) {
                    a0 += wr[d]     * c[d];
                    a1 += wr[d + 1] * c[d + 1];
                    a2 += wr[d + 2] * c[d + 2];
                    a3 += wr[d + 3] * c[d + 3];
                }
                float z = ((a0 + a1) + (a2 + a3)) + hqv[h] + hkb[h * NN + k];
                z = z > 0.f ? z : pa * z;        // PReLU
                score += W2[h] * z;
            }
            score *= vm[b * NN + k];             // key-side padding mask
        }
        __syncthreads();                         // s_sh reuse across tiles
        s_sh[t] = score;
        __syncthreads();
        // encoded[q, dlane] += sum over this tile's keys (quarter-split)
        const float* xcol = xb + (k0 + quarter * 64) * 64 + dlane;
        #pragma unroll 8
        for (int i = 0; i < 64; ++i) {
            enc += s_sh[quarter * 64 + i] * xcol[i * 64];
        }
    }

    __syncthreads();
    s_sh[t] = enc;
    __syncthreads();
    if (t < 64) {
        out[bq * 64 + t] = s_sh[t] + s_sh[64 + t] + s_sh[128 + t] + s_sh[192 + t];
    }
}

extern "C" void kernel_launch(void* const* d_in, const int* in_sizes, int n_in,
                              void* d_out, int out_size, void* d_ws, size_t ws_size,
                              hipStream_t stream) {
    // inputs: 0 past_lengths(int,unused) 1 user_embeddings 2 valid_mask
    //         3 W1 4 b1 5 prelu_a 6 W2 7 b2
    const float* x   = (const float*)d_in[1];
    const float* vmk = (const float*)d_in[2];
    const float* W1  = (const float*)d_in[3];
    const float* b1  = (const float*)d_in[4];
    const float* pa  = (const float*)d_in[5];
    const float* W2  = (const float*)d_in[6];
    const float* b2  = (const float*)d_in[7];
    float* ws  = (float*)d_ws;
    float* out = (float*)d_out;

    hipLaunchKernelGGL(k0_weights, dim3(1), dim3(256), 0, stream, W1, ws);
    hipLaunchKernelGGL(k1_proj, dim3(NB * NN / 4), dim3(256), 0, stream, x, b1, ws);
    hipLaunchKernelGGL(k2_main, dim3(NB * NN), dim3(256), 0, stream,
                       x, vmk, pa, W2, b2, ws, out);
}

// Round 2
// 122.274 us; speedup vs baseline: 3.0423x; 3.0423x over previous
//
#include <hip/hip_runtime.h>

// DIN encoder, MFMA version.
// B=8, N=512, D=64, H=64. One wave per (b,q); 16-key tiles via
// mfma_f32_16x16x32_bf16. hk folded into the MFMA via one-hot A-fragments.
#define NB 8
#define NN 512

// ws layout (float offsets)
#define WS_WMF  0        // Wm A-fragment-major fp32: [4ht*2half][64 lane][8] = 4096
#define WS_WQDT 4096     // (Wq+Wd)^T fp32 [64 d][64 h]
#define WS_WKDT 8192     // (Wk-Wd)^T fp32 [64 d][64 h]
#define WS_HQ   12288    // hq = x@(Wq+Wd)^T + b1, fp32 [B*N][64]           (262144)
#define WS_BF   274432   // B-fragments bf16 [B][32 t][4 c][64 lane][8]     (524288 bf16)
#define WS_XT   536576   // masked X tile-major bf16 [B][32 t][64 d][16 k]  (262144 bf16)
// total = 667648 floats = 2.67 MB

typedef float  fx4 __attribute__((ext_vector_type(4)));
typedef short  sx8 __attribute__((ext_vector_type(8)));

static __device__ inline unsigned short f2bf(float f) {
    unsigned int u = __float_as_uint(f);
    unsigned int r = (u + 0x7FFFu + ((u >> 16) & 1u)) >> 16;   // RNE
    return (unsigned short)r;
}
static __device__ inline float bfl(unsigned int u) { return __uint_as_float(u << 16); }
static __device__ inline float bfh(unsigned int u) { return __uint_as_float(u & 0xFFFF0000u); }

// ---- pkA: weight prep (WqdT, WkdT, Wm fragment-major fp32) ----
__global__ __launch_bounds__(256) void pkA(const float* __restrict__ W1,
                                           float* __restrict__ ws) {
    int t = threadIdx.x;
    float* wqdT = ws + WS_WQDT;
    float* wkdT = ws + WS_WKDT;
    float* wmf  = ws + WS_WMF;
    for (int i = 0; i < 16; ++i) {
        int idx = t + i * 256;            // 0..4095
        int h = idx >> 6, d = idx & 63;
        float wq = W1[h * 256 + d];
        float wk = W1[h * 256 + 64 + d];
        float wd = W1[h * 256 + 128 + d];
        wqdT[d * 64 + h] = wq + wd;
        wkdT[d * 64 + h] = wk - wd;
    }
    // Wm fragments: entry e=(slot,lane), slot=ht*2+half; lane: m=lane&15, quad=lane>>4
    for (int i = 0; i < 2; ++i) {
        int e = t + i * 256;              // 0..511
        int slot = e >> 6, lane = e & 63;
        int ht = slot >> 1, hf = slot & 1;
        int m = lane & 15, qd = lane >> 4;
        int h = ht * 16 + m;
        int dbase = hf * 32 + qd * 8;
        #pragma unroll
        for (int j = 0; j < 8; ++j)
            wmf[e * 8 + j] = W1[h * 256 + 192 + dbase + j];
    }
}

// ---- pkB: hq (fp32) and hk scattered directly into BF chunks 2/3 (bf16) ----
__global__ __launch_bounds__(256) void pkB(const float* __restrict__ x,
                                           const float* __restrict__ b1,
                                           float* __restrict__ ws) {
    const float* wqdT = ws + WS_WQDT;
    const float* wkdT = ws + WS_WKDT;
    float* hq = ws + WS_HQ;
    unsigned short* bfp = (unsigned short*)(ws + WS_BF);
    __shared__ float xs[256];
    int t = threadIdx.x;
    int r0 = blockIdx.x * 4;
    xs[t] = x[r0 * 64 + t];
    __syncthreads();
    int r = t >> 6, h = t & 63;
    const float* xr = xs + r * 64;
    float aq = b1[h], ak = 0.f;
    #pragma unroll
    for (int d = 0; d < 64; ++d) {
        float xv = xr[d];
        aq += xv * wqdT[d * 64 + h];
        ak += xv * wkdT[d * 64 + h];
    }
    int row = r0 + r;
    hq[row * 64 + h] = aq;
    // scatter hk[row][h] into B-fragment layout, chunk c=2+(h>>5)
    int bb = row >> 9, k = row & 511;
    int tt = k >> 4, nn = k & 15;
    int c  = 2 + (h >> 5);
    int qd = (h >> 3) & 3, j = h & 7;
    int ln = qd * 16 + nn;
    bfp[((((bb * 32 + tt) * 4 + c) * 64 + ln) << 3) + j] = f2bf(ak);
}

// ---- pkC: X -> BF chunks 0/1 (bf16 B-fragment layout) ----
__global__ __launch_bounds__(128) void pkC(const float* __restrict__ x,
                                           float* __restrict__ ws) {
    unsigned short* bfp = (unsigned short*)(ws + WS_BF);
    int b = blockIdx.x >> 5, t5 = blockIdx.x & 31;
    int tid = threadIdx.x;
    int c = tid >> 6, L = tid & 63;     // c in {0,1}
    int nn = L & 15, qd = L >> 4;
    const float* src = x + ((b * 512 + t5 * 16 + nn) * 64 + c * 32 + qd * 8);
    fx4 v0 = *(const fx4*)src;
    fx4 v1 = *(const fx4*)(src + 4);
    uint4 o;
    o.x = (unsigned)f2bf(v0[0]) | ((unsigned)f2bf(v0[1]) << 16);
    o.y = (unsigned)f2bf(v0[2]) | ((unsigned)f2bf(v0[3]) << 16);
    o.z = (unsigned)f2bf(v1[0]) | ((unsigned)f2bf(v1[1]) << 16);
    o.w = (unsigned)f2bf(v1[2]) | ((unsigned)f2bf(v1[3]) << 16);
    *(uint4*)(bfp + ((((b * 32 + t5) * 4 + c) * 64 + L) << 3)) = o;
}

// ---- pkD: masked X, tile-major bf16 [b][t][d][16] for the encoded epilogue ----
__global__ __launch_bounds__(256) void pkD(const float* __restrict__ x,
                                           const float* __restrict__ vm,
                                           float* __restrict__ ws) {
    unsigned short* xtp = (unsigned short*)(ws + WS_XT);
    int b = blockIdx.x >> 5, t5 = blockIdx.x & 31;
    int tid = threadIdx.x;
    int d = tid >> 2;
    int kl0 = (tid & 3) * 4;
    unsigned short u[4];
    #pragma unroll
    for (int i = 0; i < 4; ++i) {
        int k = t5 * 16 + kl0 + i;
        float v = x[(b * 512 + k) * 64 + d] * vm[b * 512 + k];
        u[i] = f2bf(v);
    }
    uint2 o;
    o.x = (unsigned)u[0] | ((unsigned)u[1] << 16);
    o.y = (unsigned)u[2] | ((unsigned)u[3] << 16);
    *(uint2*)(xtp + (((b * 32 + t5) * 64 + d) * 16 + kl0)) = o;
}

// ---- main: one wave per (b,q) ----
__global__ __launch_bounds__(256) void k2_main(const float* __restrict__ x,
                                               const float* __restrict__ prelu_a,
                                               const float* __restrict__ W2,
                                               const float* __restrict__ b2,
                                               const float* __restrict__ ws,
                                               float* __restrict__ out) {
    const int tid  = threadIdx.x;
    const int lane = tid & 63;
    const int wid  = blockIdx.x * 4 + (tid >> 6);
    const int b    = wid >> 9;
    const int rr_  = wid & 511;
    const int q    = (rr_ & 1) ? (511 - (rr_ >> 1)) : (rr_ >> 1);  // balance pairing
    const int n    = lane & 15, quad = lane >> 4;
    const int bq   = b * 512 + q;

    const float* wmf = ws + WS_WMF;
    const float* hq  = ws + WS_HQ;
    const unsigned short* bfp = (const unsigned short*)(ws + WS_BF);
    const unsigned short* xtp = (const unsigned short*)(ws + WS_XT);

    const float pa  = prelu_a[0];
    const float b2v = b2[0];

    // hq and W2 epilogue registers: h = ht*16 + quad*4 + r
    float hqr[4][4], w2r[4][4];
    #pragma unroll
    for (int ht = 0; ht < 4; ++ht) {
        fx4 vh = *(const fx4*)(hq + bq * 64 + ht * 16 + quad * 4);
        fx4 vw = *(const fx4*)(W2 + ht * 16 + quad * 4);
        #pragma unroll
        for (int r = 0; r < 4; ++r) { hqr[ht][r] = vh[r]; w2r[ht][r] = vw[r]; }
    }

    // xq for A-fragments: lane needs d = half*32 + quad*8 + j
    float xq[2][8];
    {
        const float* xp = x + bq * 64 + quad * 8;
        fx4 t0 = *(const fx4*)xp;
        fx4 t1 = *(const fx4*)(xp + 4);
        fx4 t2 = *(const fx4*)(xp + 32);
        fx4 t3 = *(const fx4*)(xp + 36);
        #pragma unroll
        for (int j = 0; j < 4; ++j) {
            xq[0][j] = t0[j]; xq[0][4 + j] = t1[j];
            xq[1][j] = t2[j]; xq[1][4 + j] = t3[j];
        }
    }

    // A fragments: A_q[h][d] = Wm[h][d] * xq[d], bf16
    sx8 afrag[4][2];
    #pragma unroll
    for (int ht = 0; ht < 4; ++ht)
        #pragma unroll
        for (int hf = 0; hf < 2; ++hf) {
            const float* wp = wmf + (((ht * 2 + hf) * 64 + lane) << 3);
            fx4 w0 = *(const fx4*)wp;
            fx4 w1 = *(const fx4*)(wp + 4);
            sx8 a;
            #pragma unroll
            for (int j = 0; j < 4; ++j) {
                a[j]     = (short)f2bf(w0[j] * xq[hf][j]);
                a[4 + j] = (short)f2bf(w1[j] * xq[hf][4 + j]);
            }
            afrag[ht][hf] = a;
        }

    // one-hot A fragments for the hk fold: chunk c=2+(ht>>1), h' = (ht>>1)*32+quad*8+j
    sx8 oh[4];
    #pragma unroll
    for (int ht = 0; ht < 4; ++ht) {
        sx8 a;
        #pragma unroll
        for (int j = 0; j < 8; ++j) {
            int hp = (ht >> 1) * 32 + quad * 8 + j;
            a[j] = (hp == ht * 16 + n) ? (short)0x3F80 : (short)0;
        }
        oh[ht] = a;
    }

    float enc = 0.f;
    const int tmax = q >> 4;
    for (int t = 0; t <= tmax; ++t) {
        const unsigned short* fb = bfp + ((((b * 32 + t) * 4) * 64 + lane) << 3);
        sx8 bf0 = *(const sx8*)(fb);
        sx8 bf1 = *(const sx8*)(fb + 512);
        sx8 bf2 = *(const sx8*)(fb + 1024);
        sx8 bf3 = *(const sx8*)(fb + 1536);

        fx4 acc[4];
        #pragma unroll
        for (int ht = 0; ht < 4; ++ht) acc[ht] = (fx4){0.f, 0.f, 0.f, 0.f};
        #pragma unroll
        for (int ht = 0; ht < 4; ++ht)
            acc[ht] = __builtin_amdgcn_mfma_f32_16x16x32_bf16(afrag[ht][0], bf0, acc[ht], 0, 0, 0);
        #pragma unroll
        for (int ht = 0; ht < 4; ++ht)
            acc[ht] = __builtin_amdgcn_mfma_f32_16x16x32_bf16(afrag[ht][1], bf1, acc[ht], 0, 0, 0);
        #pragma unroll
        for (int ht = 0; ht < 4; ++ht)
            acc[ht] = __builtin_amdgcn_mfma_f32_16x16x32_bf16(oh[ht], (ht < 2) ? bf2 : bf3, acc[ht], 0, 0, 0);

        // score partial: lane holds h = ht*16 + quad*4 + r for key t*16+n
        float s = 0.f;
        #pragma unroll
        for (int ht = 0; ht < 4; ++ht)
            #pragma unroll
            for (int r = 0; r < 4; ++r) {
                float z = acc[ht][r] + hqr[ht][r];
                z = z > 0.f ? z : z * pa;
                s = fmaf(w2r[ht][r], z, s);
            }
        s += __shfl_xor(s, 16, 64);
        s += __shfl_xor(s, 32, 64);
        int kk = t * 16 + n;
        s = (kk <= q) ? (s + b2v) : 0.f;   // causal mask + bias (vm folded into XT)

        // encoded: lane = d; keys j of this tile broadcast via readlane
        const uint4* px = (const uint4*)(xtp + (((b * 32 + t) * 64 + lane) << 4));
        uint4 xa = px[0], xb = px[1];
        float xv[16];
        xv[0]  = bfl(xa.x); xv[1]  = bfh(xa.x);
        xv[2]  = bfl(xa.y); xv[3]  = bfh(xa.y);
        xv[4]  = bfl(xa.z); xv[5]  = bfh(xa.z);
        xv[6]  = bfl(xa.w); xv[7]  = bfh(xa.w);
        xv[8]  = bfl(xb.x); xv[9]  = bfh(xb.x);
        xv[10] = bfl(xb.y); xv[11] = bfh(xb.y);
        xv[12] = bfl(xb.z); xv[13] = bfh(xb.z);
        xv[14] = bfl(xb.w); xv[15] = bfh(xb.w);
        #pragma unroll
        for (int j = 0; j < 16; ++j) {
            float sj = __uint_as_float(__builtin_amdgcn_readlane(__float_as_uint(s), j));
            enc = fmaf(sj, xv[j], enc);
        }
    }
    out[bq * 64 + lane] = enc;
}

extern "C" void kernel_launch(void* const* d_in, const int* in_sizes, int n_in,
                              void* d_out, int out_size, void* d_ws, size_t ws_size,
                              hipStream_t stream) {
    const float* x   = (const float*)d_in[1];
    const float* vmk = (const float*)d_in[2];
    const float* W1  = (const float*)d_in[3];
    const float* b1  = (const float*)d_in[4];
    const float* pa  = (const float*)d_in[5];
    const float* W2  = (const float*)d_in[6];
    const float* b2  = (const float*)d_in[7];
    float* ws  = (float*)d_ws;
    float* out = (float*)d_out;

    hipLaunchKernelGGL(pkA, dim3(1), dim3(256), 0, stream, W1, ws);
    hipLaunchKernelGGL(pkB, dim3(NB * NN / 4), dim3(256), 0, stream, x, b1, ws);
    hipLaunchKernelGGL(pkC, dim3(NB * 32), dim3(128), 0, stream, x, ws);
    hipLaunchKernelGGL(pkD, dim3(NB * 32), dim3(256), 0, stream, x, vmk, ws);
    hipLaunchKernelGGL(k2_main, dim3(NB * NN / 4), dim3(256), 0, stream,
                       x, pa, W2, b2, ws, out);
}